// Round 4
// baseline (330.486 us; speedup 1.0000x reference)
//
#include <hip/hip_runtime.h>
#include <hip/hip_bf16.h>
#include <stdint.h>

typedef unsigned short u16;
typedef __attribute__((ext_vector_type(8))) __bf16 bf16x8;
typedef __attribute__((ext_vector_type(4))) float f32x4;

#define LOG2E 1.4426950408889634f

__device__ __forceinline__ float bf2f(u16 u) {
  union { uint32_t u; float f; } v; v.u = ((uint32_t)u) << 16;
  return v.f;
}

// packed cvt: two fp32 -> one u32 holding (lo=a, hi=b) bf16
__device__ __forceinline__ uint32_t pk2(float a, float b) {
  union { __hip_bfloat162 h; uint32_t u; } x;
  x.h = __float22bfloat162_rn(make_float2(a, b));
  return x.u;
}

__device__ __forceinline__ void gl_lds16(const void* g, void* l) {
  __builtin_amdgcn_global_load_lds((const __attribute__((address_space(1))) void*)g,
                                   (__attribute__((address_space(3))) void*)l,
                                   16, 0, 0);
}

__device__ __forceinline__ f32x4 mfma16(bf16x8 a, bf16x8 b, f32x4 c) {
  return __builtin_amdgcn_mfma_f32_16x16x32_bf16(a, b, c, 0, 0, 0);
}

// ---------------- fp32 -> bf16 elementwise (x) ----------------
__global__ void cvt_bf16(const float* __restrict__ src, u16* __restrict__ dst) {
  int i = (blockIdx.x * 256 + threadIdx.x) * 4;
  float4 f = *(const float4*)(src + i);
  uint2 o;
  o.x = pk2(f.x, f.y);
  o.y = pk2(f.z, f.w);
  *(uint2*)(dst + i) = o;
}

// ---------------- transpose + convert: W[k][n] fp32 -> Wt[n][k] bf16 ----------------
// coalesced 16B/lane writes (8 contiguous k per lane)
__global__ void transpose_cvt(const float* __restrict__ W0, const float* __restrict__ W1,
                              const float* __restrict__ W2, const float* __restrict__ W3,
                              u16* __restrict__ out) {
  __shared__ float tile[64][65];
  int z = blockIdx.z;
  const float* W = (z == 0) ? W0 : (z == 1) ? W1 : (z == 2) ? W2 : W3;
  u16* dst = out + (size_t)z * 2048 * 2048;
  int k0 = blockIdx.y * 64, n0 = blockIdx.x * 64;
  int lx = threadIdx.x & 63, ly = threadIdx.x >> 6;
#pragma unroll
  for (int p = 0; p < 16; ++p) {
    int row = p * 4 + ly;
    tile[row][lx] = W[(size_t)(k0 + row) * 2048 + n0 + lx];
  }
  __syncthreads();
  int kc = threadIdx.x & 7;        // 8-wide k chunk
  int rbase = threadIdx.x >> 3;    // 0..31
#pragma unroll
  for (int p = 0; p < 2; ++p) {
    int n = rbase + p * 32;        // n-local row
    uint4 o;
    o.x = pk2(tile[kc * 8 + 0][n], tile[kc * 8 + 1][n]);
    o.y = pk2(tile[kc * 8 + 2][n], tile[kc * 8 + 3][n]);
    o.z = pk2(tile[kc * 8 + 4][n], tile[kc * 8 + 5][n]);
    o.w = pk2(tile[kc * 8 + 6][n], tile[kc * 8 + 7][n]);
    *(uint4*)(dst + (size_t)(n0 + n) * 2048 + k0 + kc * 8) = o;
  }
}

// ---------------- bf16 GEMM, m97-style: C = A[M][K] @ Bt[N][K]^T ----------------
__launch_bounds__(256, 2)
__global__ void gemm_bt(const u16* __restrict__ A, const u16* __restrict__ Bt,
                        int mode,
                        const float* __restrict__ b0, const float* __restrict__ b1,
                        const float* __restrict__ b2,
                        float* __restrict__ outF, u16* __restrict__ outQ,
                        u16* __restrict__ outK, u16* __restrict__ outVT) {
  extern __shared__ char smem[];
  u16* As = (u16*)smem;              // [128][64] bf16, 16B-chunk XOR swizzled
  u16* Bs = (u16*)(smem + 16384);
  const int K = 2048;
  const int tid = threadIdx.x;
  const int lane = tid & 63, wid = tid >> 6;
  const int c = lane & 15, q = lane >> 4;
  const int wm = wid >> 1, wn = wid & 1;
  const int tm = blockIdx.y, tn = blockIdx.x;
  const size_t Abase = (size_t)tm * 128 * K;
  const size_t Bbase = (size_t)tn * 128 * K;

  f32x4 acc[4][4] = {};

  for (int kt = 0; kt < K / 64; ++kt) {
#pragma unroll
    for (int t = 0; t < 4; ++t) {
      int slot = wid * 256 + t * 64 + lane;
      int row = slot >> 3, cs = slot & 7;
      int cc = cs ^ (row & 7);
      const u16* ga = A + Abase + (size_t)row * K + kt * 64 + cc * 8;
      gl_lds16(ga, (char*)As + (size_t)(wid * 256 + t * 64) * 16);
      const u16* gb = Bt + Bbase + (size_t)row * K + kt * 64 + cc * 8;
      gl_lds16(gb, (char*)Bs + (size_t)(wid * 256 + t * 64) * 16);
    }
    __syncthreads();
#pragma unroll
    for (int kc = 0; kc < 2; ++kc) {
      bf16x8 af[4], bfr[4];
#pragma unroll
      for (int i = 0; i < 4; ++i) {
        int rowa = wm * 64 + i * 16 + c;
        int cha = ((kc << 2) | q) ^ (rowa & 7);
        af[i] = *(const bf16x8*)((const char*)As + rowa * 128 + cha * 16);
        int rowb = wn * 64 + i * 16 + c;
        int chb = ((kc << 2) | q) ^ (rowb & 7);
        bfr[i] = *(const bf16x8*)((const char*)Bs + rowb * 128 + chb * 16);
      }
#pragma unroll
      for (int i = 0; i < 4; ++i)
#pragma unroll
        for (int j = 0; j < 4; ++j)
          acc[i][j] = mfma16(af[i], bfr[j], acc[i][j]);
    }
    __syncthreads();
  }

  if (mode == 0) {
#pragma unroll
    for (int i = 0; i < 4; ++i) {
      int rowg = tm * 128 + wm * 64 + i * 16 + q * 4;
#pragma unroll
      for (int j = 0; j < 4; ++j) {
        int colg = tn * 128 + wn * 64 + j * 16 + c;
        float bias = b0[colg];
#pragma unroll
        for (int r = 0; r < 4; ++r)
          outF[(size_t)(rowg + r) * 2048 + colg] = acc[i][j][r] + bias;
      }
    }
  } else {
    int proj = tn >> 4;
    int h = tn & 15;
    const float* bias = (proj == 0) ? b0 : (proj == 1) ? b1 : b2;
    if (proj < 2) {
      u16* out = (proj == 0) ? outQ : outK;
      float scale = (proj == 0) ? 0.08838834764831845f : 1.0f;
#pragma unroll
      for (int i = 0; i < 4; ++i) {
        int s0 = tm * 128 + wm * 64 + i * 16 + q * 4;
#pragma unroll
        for (int j = 0; j < 4; ++j) {
          int d = wn * 64 + j * 16 + c;
          float bv = bias[h * 128 + d];
          uint32_t p01 = pk2((acc[i][j][0] + bv) * scale, (acc[i][j][1] + bv) * scale);
          uint32_t p23 = pk2((acc[i][j][2] + bv) * scale, (acc[i][j][3] + bv) * scale);
          u16* o = out + ((size_t)h * 2048 + s0) * 128 + d;
          o[0]       = (u16)p01;
          o[128]     = (u16)(p01 >> 16);
          o[256]     = (u16)p23;
          o[384]     = (u16)(p23 >> 16);
        }
      }
    } else {
      // V: transpose via LDS -> Vt[h][d][s]
      u16* Cs = (u16*)smem;  // [128][136]
#pragma unroll
      for (int i = 0; i < 4; ++i) {
        int sl = wm * 64 + i * 16 + q * 4;
#pragma unroll
        for (int j = 0; j < 4; ++j) {
          int dl = wn * 64 + j * 16 + c;
          float bv = bias[h * 128 + dl];
          uint2 pk;
          pk.x = pk2(acc[i][j][0] + bv, acc[i][j][1] + bv);
          pk.y = pk2(acc[i][j][2] + bv, acc[i][j][3] + bv);
          *(uint2*)(Cs + dl * 136 + sl) = pk;
        }
      }
      __syncthreads();
#pragma unroll
      for (int rr = 0; rr < 8; ++rr) {
        int d = rr * 16 + (tid >> 4);
        int sc = (tid & 15) * 8;
        uint4 vv = *(const uint4*)(Cs + d * 136 + sc);
        *(uint4*)(outVT + ((size_t)(h * 128 + d)) * 2048 + tm * 128 + sc) = vv;
      }
    }
  }
}

// ---------------- flash attention, causal, split-K(2), max-free softmax ----------------
// Computes O^T in PV (operand-swapped MFMA) so epilogue stores are packed.
// Stores RAW (unnormalized) partial O + row-sum l; combine divides by (l0+l1).
// NOTE: qt=0/split1 rows 0..63 are fully masked -> l=0, oacc=0. Raw store keeps
// that benign (0 + O0)/(l0 + 0); NEVER normalize per-split here (0*1/0 = NaN).
__launch_bounds__(256, 3)
__global__ void attn_kernel(const u16* __restrict__ Qb, const u16* __restrict__ Kb,
                            const u16* __restrict__ Vt,
                            u16* __restrict__ Op0, u16* __restrict__ Op1,
                            float* __restrict__ lp0, float* __restrict__ lp1) {
  extern __shared__ char smem[];
  u16* Ks = (u16*)smem;              // [64 keys][128 dk]  16 KB, swizzled
  u16* Vs = (u16*)(smem + 16384);    // [128 dk][64 keys]  16 KB, swizzled
  u16* Ps = (u16*)(smem + 32768);    // [4 waves][32][72]  18432 B
  int b = blockIdx.x;
  int split, qt, h;
  if (b < 256) { split = 0; qt = b >> 4; h = b & 15; }
  else { split = 1; int idx = b - 256; qt = 15 - (idx >> 4); h = idx & 15; }
  u16* Op = split ? Op1 : Op0;
  float* lp = split ? lp1 : lp0;
  const int ktBase = split ? (qt + 1) : 0;
  const int ntiles = qt + 1;

  const int tid = threadIdx.x, lane = tid & 63, wid = tid >> 6;
  const int c = lane & 15, q = lane >> 4;

  // Q fragments in registers: wave owns rows [qt*128 + wid*32, +32)
  bf16x8 qf[2][4];
#pragma unroll
  for (int i = 0; i < 2; ++i) {
    int s = qt * 128 + wid * 32 + i * 16 + c;
    const u16* qrow = Qb + ((size_t)h * 2048 + s) * 128;
#pragma unroll
    for (int kc = 0; kc < 4; ++kc)
      qf[i][kc] = *(const bf16x8*)(qrow + kc * 32 + q * 8);
  }

  f32x4 oacc[2][8] = {};   // O^T: oacc[i][jo][r] = O[qrow=i*16+c][d=jo*16+q*4+r]
  float lst[2][4] = {};

  for (int tt = 0; tt < ntiles; ++tt) {
    const int kt = ktBase + tt;
    if (tt) __syncthreads();
#pragma unroll
    for (int t = 0; t < 4; ++t) {
      int slot = (wid * 4 + t) * 64 + lane;
      int rowk = slot >> 4, csk = slot & 15;
      int cck = csk ^ (rowk & 7);
      const u16* gk = Kb + ((size_t)h * 2048 + kt * 64 + rowk) * 128 + cck * 8;
      gl_lds16(gk, (char*)Ks + (size_t)((wid * 4 + t) * 64) * 16);
      int rowv = slot >> 3, csv = slot & 7;
      int ccv = csv ^ (rowv & 7);
      const u16* gv = Vt + ((size_t)(h * 128 + rowv)) * 2048 + kt * 64 + ccv * 8;
      gl_lds16(gv, (char*)Vs + (size_t)((wid * 4 + t) * 64) * 16);
    }
    __syncthreads();

    // S = Q K^T   (1/sqrt(dk) folded into Q)
    f32x4 sacc[2][4] = {};
#pragma unroll
    for (int kc = 0; kc < 4; ++kc) {
      bf16x8 bfr[4];
#pragma unroll
      for (int j = 0; j < 4; ++j) {
        int row = j * 16 + c;
        int ch = ((kc << 2) | q) ^ (row & 7);
        bfr[j] = *(const bf16x8*)((const char*)Ks + row * 256 + ch * 16);
      }
#pragma unroll
      for (int i = 0; i < 2; ++i)
#pragma unroll
        for (int j = 0; j < 4; ++j)
          sacc[i][j] = mfma16(qf[i][kc], bfr[j], sacc[i][j]);
    }

    // causal mask (only diagonal-crossing key-tiles)
    if (kt >= 2 * qt) {
#pragma unroll
      for (int i = 0; i < 2; ++i)
#pragma unroll
        for (int j = 0; j < 4; ++j) {
          int key = kt * 64 + j * 16 + c;
#pragma unroll
          for (int r = 0; r < 4; ++r) {
            int qrow = qt * 128 + wid * 32 + i * 16 + q * 4 + r;
            if (key > qrow) sacc[i][j][r] = -1e30f;
          }
        }
    }

    // max-free softmax: P = exp(S); per-lane partial row-sums
#pragma unroll
    for (int i = 0; i < 2; ++i)
#pragma unroll
      for (int j = 0; j < 4; ++j)
#pragma unroll
        for (int r = 0; r < 4; ++r) {
          float p = __builtin_amdgcn_exp2f(sacc[i][j][r] * LOG2E);
          sacc[i][j][r] = p;
          lst[i][r] += p;
        }

    // P -> LDS (bf16), C-layout -> A-layout round trip (per-wave private slab)
#pragma unroll
    for (int i = 0; i < 2; ++i)
#pragma unroll
      for (int j = 0; j < 4; ++j) {
        uint32_t p01 = pk2(sacc[i][j][0], sacc[i][j][1]);
        uint32_t p23 = pk2(sacc[i][j][2], sacc[i][j][3]);
        u16* pp = Ps + wid * 2304 + (i * 16 + q * 4) * 72 + j * 16 + c;
        pp[0]   = (u16)p01;
        pp[72]  = (u16)(p01 >> 16);
        pp[144] = (u16)p23;
        pp[216] = (u16)(p23 >> 16);
      }

    // O^T += V^T @ P^T  (operand-swapped: m = d, n = qrow)
#pragma unroll
    for (int kc = 0; kc < 2; ++kc) {
      bf16x8 af[2], bv[8];
#pragma unroll
      for (int i = 0; i < 2; ++i)
        af[i] = *(const bf16x8*)((const char*)Ps + wid * 4608 + (i * 16 + c) * 144 +
                                 kc * 64 + q * 16);
#pragma unroll
      for (int jo = 0; jo < 8; ++jo) {
        int row = jo * 16 + c;
        int ch = ((kc << 2) | q) ^ (row & 7);
        bv[jo] = *(const bf16x8*)((const char*)Vs + row * 128 + ch * 16);
      }
#pragma unroll
      for (int i = 0; i < 2; ++i)
#pragma unroll
        for (int jo = 0; jo < 8; ++jo)
          oacc[i][jo] = mfma16(bv[jo], af[i], oacc[i][jo]);
    }
  }

  // epilogue: reduce l over c-lanes and store; store RAW O packed (4 contig d / lane)
#pragma unroll
  for (int i = 0; i < 2; ++i)
#pragma unroll
    for (int r = 0; r < 4; ++r) {
      float l = lst[i][r];
      l += __shfl_xor(l, 1);
      l += __shfl_xor(l, 2);
      l += __shfl_xor(l, 4);
      l += __shfl_xor(l, 8);
      if (c == 0)
        lp[(size_t)h * 2048 + qt * 128 + wid * 32 + i * 16 + q * 4 + r] = l;
    }
#pragma unroll
  for (int i = 0; i < 2; ++i) {
    int s = qt * 128 + wid * 32 + i * 16 + c;
#pragma unroll
    for (int jo = 0; jo < 8; ++jo) {
      uint2 o;
      o.x = pk2(oacc[i][jo][0], oacc[i][jo][1]);
      o.y = pk2(oacc[i][jo][2], oacc[i][jo][3]);
      *(uint2*)(Op + ((size_t)h * 2048 + s) * 128 + jo * 16 + q * 4) = o;
    }
  }
}

// ---------------- combine: AO = (O0+O1)/(l0+l1), bf16 out [s][h*128+d] ----------------
__global__ void attn_combine(const u16* __restrict__ Op0, const u16* __restrict__ Op1,
                             const float* __restrict__ lp0, const float* __restrict__ lp1,
                             u16* __restrict__ AO) {
  int g = blockIdx.x * 256 + threadIdx.x;   // 524288 threads, 8 elems each
  int row = g >> 4;                          // h*2048 + s
  int dd = (g & 15) * 8;
  int h = row >> 11, s = row & 2047;
  float inv = 1.0f / (lp0[row] + lp1[row]);
  uint4 a = *(const uint4*)(Op0 + (size_t)row * 128 + dd);
  uint4 bb = *(const uint4*)(Op1 + (size_t)row * 128 + dd);
  const u16* pa = (const u16*)&a;
  const u16* pb = (const u16*)&bb;
  uint4 res;
  uint32_t* pr = (uint32_t*)&res;
#pragma unroll
  for (int t = 0; t < 4; ++t)
    pr[t] = pk2((bf2f(pa[2 * t]) + bf2f(pb[2 * t])) * inv,
                (bf2f(pa[2 * t + 1]) + bf2f(pb[2 * t + 1])) * inv);
  *(uint4*)(AO + (size_t)s * 2048 + h * 128 + dd) = res;
}

extern "C" void kernel_launch(void* const* d_in, const int* in_sizes, int n_in,
                              void* d_out, int out_size, void* d_ws, size_t ws_size,
                              hipStream_t stream) {
  const float* x  = (const float*)d_in[0];
  const float* Wq = (const float*)d_in[1];
  const float* bq = (const float*)d_in[2];
  const float* Wk = (const float*)d_in[3];
  const float* bk = (const float*)d_in[4];
  const float* Wv = (const float*)d_in[5];
  const float* bv = (const float*)d_in[6];
  const float* Wo = (const float*)d_in[7];
  const float* bo = (const float*)d_in[8];

  char* ws = (char*)d_ws;
  u16* xb = (u16*)(ws);                          // x bf16            0- 8 MB
  u16* wt = (u16*)(ws + (size_t)8  * 1048576);   // Wq/k/v/o^T bf16   8-40 MB
  u16* Qb = (u16*)(ws + (size_t)40 * 1048576);   // Q [h][s][d]      40-48 MB
  u16* Kb = (u16*)(ws + (size_t)48 * 1048576);   // K [h][s][d]      48-56 MB
  u16* Vt = (u16*)(ws + (size_t)56 * 1048576);   // V^T [h][d][s]    56-64 MB
  u16* AO = (u16*)(ws + (size_t)64 * 1048576);   // attn out [s][D]  64-72 MB
  u16* Op0 = (u16*)(ws);                         // partial O split0 (over xb)
  u16* Op1 = (u16*)(ws + (size_t)8 * 1048576);   // partial O split1 (over Wq^T)
  float* l0 = (float*)(ws + (size_t)16 * 1048576);
  float* l1 = (float*)(ws + (size_t)16 * 1048576 + 131072);

  cvt_bf16<<<4096, 256, 0, stream>>>(x, xb);
  transpose_cvt<<<dim3(32, 32, 4), 256, 0, stream>>>(Wq, Wk, Wv, Wo, wt);
  gemm_bt<<<dim3(48, 16), 256, 34816, stream>>>(xb, wt, 1, bq, bk, bv,
                                                nullptr, Qb, Kb, Vt);
  attn_kernel<<<512, 256, 51200, stream>>>(Qb, Kb, Vt, Op0, Op1, l0, l1);
  attn_combine<<<2048, 256, 0, stream>>>(Op0, Op1, l0, l1, AO);
  gemm_bt<<<dim3(16, 16), 256, 34816, stream>>>(AO, wt + (size_t)3 * 2048 * 2048, 0,
                                                bo, nullptr, nullptr,
                                                (float*)d_out, nullptr, nullptr, nullptr);
}

// Round 5
// 262.098 us; speedup vs baseline: 1.2609x; 1.2609x over previous
//
#include <hip/hip_runtime.h>
#include <hip/hip_bf16.h>
#include <stdint.h>

typedef unsigned short u16;
typedef __attribute__((ext_vector_type(8))) __bf16 bf16x8;
typedef __attribute__((ext_vector_type(4))) float f32x4;

#define LOG2E 1.4426950408889634f

__device__ __forceinline__ float bf2f(u16 u) {
  union { uint32_t u; float f; } v; v.u = ((uint32_t)u) << 16;
  return v.f;
}

// packed cvt: two fp32 -> one u32 holding (lo=a, hi=b) bf16
__device__ __forceinline__ uint32_t pk2(float a, float b) {
  union { __hip_bfloat162 h; uint32_t u; } x;
  x.h = __float22bfloat162_rn(make_float2(a, b));
  return x.u;
}

__device__ __forceinline__ void gl_lds16(const void* g, void* l) {
  __builtin_amdgcn_global_load_lds((const __attribute__((address_space(1))) void*)g,
                                   (__attribute__((address_space(3))) void*)l,
                                   16, 0, 0);
}

__device__ __forceinline__ f32x4 mfma16(bf16x8 a, bf16x8 b, f32x4 c) {
  return __builtin_amdgcn_mfma_f32_16x16x32_bf16(a, b, c, 0, 0, 0);
}

// ---------------- fp32 -> bf16 elementwise (x) ----------------
__global__ void cvt_bf16(const float* __restrict__ src, u16* __restrict__ dst) {
  int i = (blockIdx.x * 256 + threadIdx.x) * 4;
  float4 f = *(const float4*)(src + i);
  uint2 o;
  o.x = pk2(f.x, f.y);
  o.y = pk2(f.z, f.w);
  *(uint2*)(dst + i) = o;
}

// ---------------- transpose + convert: W[k][n] fp32 -> Wt[n][k] bf16 ----------------
__global__ void transpose_cvt(const float* __restrict__ W0, const float* __restrict__ W1,
                              const float* __restrict__ W2, const float* __restrict__ W3,
                              u16* __restrict__ out) {
  __shared__ float tile[64][65];
  int z = blockIdx.z;
  const float* W = (z == 0) ? W0 : (z == 1) ? W1 : (z == 2) ? W2 : W3;
  u16* dst = out + (size_t)z * 2048 * 2048;
  int k0 = blockIdx.y * 64, n0 = blockIdx.x * 64;
  int lx = threadIdx.x & 63, ly = threadIdx.x >> 6;
#pragma unroll
  for (int p = 0; p < 16; ++p) {
    int row = p * 4 + ly;
    tile[row][lx] = W[(size_t)(k0 + row) * 2048 + n0 + lx];
  }
  __syncthreads();
  int kc = threadIdx.x & 7;        // 8-wide k chunk
  int rbase = threadIdx.x >> 3;    // 0..31
#pragma unroll
  for (int p = 0; p < 2; ++p) {
    int n = rbase + p * 32;        // n-local row
    uint4 o;
    o.x = pk2(tile[kc * 8 + 0][n], tile[kc * 8 + 1][n]);
    o.y = pk2(tile[kc * 8 + 2][n], tile[kc * 8 + 3][n]);
    o.z = pk2(tile[kc * 8 + 4][n], tile[kc * 8 + 5][n]);
    o.w = pk2(tile[kc * 8 + 6][n], tile[kc * 8 + 7][n]);
    *(uint4*)(dst + (size_t)(n0 + n) * 2048 + k0 + kc * 8) = o;
  }
}

// ---------------- bf16 GEMM, m97-style: C = A[M][K] @ Bt[N][K]^T ----------------
__launch_bounds__(256, 2)
__global__ void gemm_bt(const u16* __restrict__ A, const u16* __restrict__ Bt,
                        int mode,
                        const float* __restrict__ b0, const float* __restrict__ b1,
                        const float* __restrict__ b2,
                        float* __restrict__ outF, u16* __restrict__ outQ,
                        u16* __restrict__ outK, u16* __restrict__ outVT) {
  extern __shared__ char smem[];
  u16* As = (u16*)smem;              // [128][64] bf16, 16B-chunk XOR swizzled
  u16* Bs = (u16*)(smem + 16384);
  const int K = 2048;
  const int tid = threadIdx.x;
  const int lane = tid & 63, wid = tid >> 6;
  const int c = lane & 15, q = lane >> 4;
  const int wm = wid >> 1, wn = wid & 1;
  const int tm = blockIdx.y, tn = blockIdx.x;
  const size_t Abase = (size_t)tm * 128 * K;
  const size_t Bbase = (size_t)tn * 128 * K;

  f32x4 acc[4][4] = {};

  for (int kt = 0; kt < K / 64; ++kt) {
#pragma unroll
    for (int t = 0; t < 4; ++t) {
      int slot = wid * 256 + t * 64 + lane;
      int row = slot >> 3, cs = slot & 7;
      int cc = cs ^ (row & 7);
      const u16* ga = A + Abase + (size_t)row * K + kt * 64 + cc * 8;
      gl_lds16(ga, (char*)As + (size_t)(wid * 256 + t * 64) * 16);
      const u16* gb = Bt + Bbase + (size_t)row * K + kt * 64 + cc * 8;
      gl_lds16(gb, (char*)Bs + (size_t)(wid * 256 + t * 64) * 16);
    }
    __syncthreads();
#pragma unroll
    for (int kc = 0; kc < 2; ++kc) {
      bf16x8 af[4], bfr[4];
#pragma unroll
      for (int i = 0; i < 4; ++i) {
        int rowa = wm * 64 + i * 16 + c;
        int cha = ((kc << 2) | q) ^ (rowa & 7);
        af[i] = *(const bf16x8*)((const char*)As + rowa * 128 + cha * 16);
        int rowb = wn * 64 + i * 16 + c;
        int chb = ((kc << 2) | q) ^ (rowb & 7);
        bfr[i] = *(const bf16x8*)((const char*)Bs + rowb * 128 + chb * 16);
      }
#pragma unroll
      for (int i = 0; i < 4; ++i)
#pragma unroll
        for (int j = 0; j < 4; ++j)
          acc[i][j] = mfma16(af[i], bfr[j], acc[i][j]);
    }
    __syncthreads();
  }

  if (mode == 0) {
#pragma unroll
    for (int i = 0; i < 4; ++i) {
      int rowg = tm * 128 + wm * 64 + i * 16 + q * 4;
#pragma unroll
      for (int j = 0; j < 4; ++j) {
        int colg = tn * 128 + wn * 64 + j * 16 + c;
        float bias = b0[colg];
#pragma unroll
        for (int r = 0; r < 4; ++r)
          outF[(size_t)(rowg + r) * 2048 + colg] = acc[i][j][r] + bias;
      }
    }
  } else {
    int proj = tn >> 4;
    int h = tn & 15;
    const float* bias = (proj == 0) ? b0 : (proj == 1) ? b1 : b2;
    if (proj < 2) {
      u16* out = (proj == 0) ? outQ : outK;
      float scale = (proj == 0) ? 0.08838834764831845f : 1.0f;
#pragma unroll
      for (int i = 0; i < 4; ++i) {
        int s0 = tm * 128 + wm * 64 + i * 16 + q * 4;
#pragma unroll
        for (int j = 0; j < 4; ++j) {
          int d = wn * 64 + j * 16 + c;
          float bv = bias[h * 128 + d];
          uint32_t p01 = pk2((acc[i][j][0] + bv) * scale, (acc[i][j][1] + bv) * scale);
          uint32_t p23 = pk2((acc[i][j][2] + bv) * scale, (acc[i][j][3] + bv) * scale);
          u16* o = out + ((size_t)h * 2048 + s0) * 128 + d;
          o[0]       = (u16)p01;
          o[128]     = (u16)(p01 >> 16);
          o[256]     = (u16)p23;
          o[384]     = (u16)(p23 >> 16);
        }
      }
    } else {
      // V: transpose via LDS -> Vt[h][d][s]
      u16* Cs = (u16*)smem;  // [128][136]
#pragma unroll
      for (int i = 0; i < 4; ++i) {
        int sl = wm * 64 + i * 16 + q * 4;
#pragma unroll
        for (int j = 0; j < 4; ++j) {
          int dl = wn * 64 + j * 16 + c;
          float bv = bias[h * 128 + dl];
          uint2 pk;
          pk.x = pk2(acc[i][j][0] + bv, acc[i][j][1] + bv);
          pk.y = pk2(acc[i][j][2] + bv, acc[i][j][3] + bv);
          *(uint2*)(Cs + dl * 136 + sl) = pk;
        }
      }
      __syncthreads();
#pragma unroll
      for (int rr = 0; rr < 8; ++rr) {
        int d = rr * 16 + (tid >> 4);
        int sc = (tid & 15) * 8;
        uint4 vv = *(const uint4*)(Cs + d * 136 + sc);
        *(uint4*)(outVT + ((size_t)(h * 128 + d)) * 2048 + tm * 128 + sc) = vv;
      }
    }
  }
}

// ---------------- flash attention, causal, split-K(4), max-free softmax ----------------
// grid 1024: sp = b>>8 (split 0..3), idx = b&255, qt = idx>>4 (reversed for sp>=2),
// h = idx&15. Split sp covers key-tiles [T*sp/4, T*(sp+1)/4), T = 2qt+2.
// Stores RAW partial O (bf16) + row-sum l (fp32, in d_out scratch); combine divides
// by sum of l. Empty splits store zeros — benign. NEVER normalize per-split (0/0).
// __launch_bounds__(256,2): (256,3) caps unified regs at 168 -> ~50-reg scratch
// spill in K-loop (round 4: VGPR 84, WRITE_SIZE 94 MB, 2x slower). 216 <= 256 ok.
__launch_bounds__(256, 2)
__global__ void attn_kernel(const u16* __restrict__ Qb, const u16* __restrict__ Kb,
                            const u16* __restrict__ Vt,
                            u16* __restrict__ Opb, float* __restrict__ lpb) {
  extern __shared__ char smem[];
  u16* Ks = (u16*)smem;              // [64 keys][128 dk]  16 KB, swizzled
  u16* Vs = (u16*)(smem + 16384);    // [128 dk][64 keys]  16 KB, swizzled
  u16* Ps = (u16*)(smem + 32768);    // [4 waves][32][72]  18432 B
  int b = blockIdx.x;
  int sp = b >> 8;
  int idx = b & 255;
  int qt = idx >> 4;
  if (sp >= 2) qt = 15 - qt;         // balance dispatch order
  int h = idx & 15;
  int T = 2 * qt + 2;
  const int ktBase = (T * sp) >> 2;
  const int ktEnd = (T * (sp + 1)) >> 2;
  const int ntiles = ktEnd - ktBase;
  u16* Op = Opb + (size_t)sp * 4194304;        // 8 MB stride (16*2048*128 u16)
  float* lp = lpb + (size_t)sp * 32768;

  const int tid = threadIdx.x, lane = tid & 63, wid = tid >> 6;
  const int c = lane & 15, q = lane >> 4;

  // Q fragments in registers: wave owns rows [qt*128 + wid*32, +32)
  bf16x8 qf[2][4];
#pragma unroll
  for (int i = 0; i < 2; ++i) {
    int s = qt * 128 + wid * 32 + i * 16 + c;
    const u16* qrow = Qb + ((size_t)h * 2048 + s) * 128;
#pragma unroll
    for (int kc = 0; kc < 4; ++kc)
      qf[i][kc] = *(const bf16x8*)(qrow + kc * 32 + q * 8);
  }

  f32x4 oacc[2][8] = {};   // O^T: oacc[i][jo][r] = O[qrow=i*16+c][d=jo*16+q*4+r]
  float lst[2][4] = {};

  for (int tt = 0; tt < ntiles; ++tt) {
    const int kt = ktBase + tt;
    if (tt) __syncthreads();
#pragma unroll
    for (int t = 0; t < 4; ++t) {
      int slot = (wid * 4 + t) * 64 + lane;
      int rowk = slot >> 4, csk = slot & 15;
      int cck = csk ^ (rowk & 7);
      const u16* gk = Kb + ((size_t)h * 2048 + kt * 64 + rowk) * 128 + cck * 8;
      gl_lds16(gk, (char*)Ks + (size_t)((wid * 4 + t) * 64) * 16);
      int rowv = slot >> 3, csv = slot & 7;
      int ccv = csv ^ (rowv & 7);
      const u16* gv = Vt + ((size_t)(h * 128 + rowv)) * 2048 + kt * 64 + ccv * 8;
      gl_lds16(gv, (char*)Vs + (size_t)((wid * 4 + t) * 64) * 16);
    }
    __syncthreads();

    // S = Q K^T   (1/sqrt(dk) folded into Q)
    f32x4 sacc[2][4] = {};
#pragma unroll
    for (int kc = 0; kc < 4; ++kc) {
      bf16x8 bfr[4];
#pragma unroll
      for (int j = 0; j < 4; ++j) {
        int row = j * 16 + c;
        int ch = ((kc << 2) | q) ^ (row & 7);
        bfr[j] = *(const bf16x8*)((const char*)Ks + row * 256 + ch * 16);
      }
#pragma unroll
      for (int i = 0; i < 2; ++i)
#pragma unroll
        for (int j = 0; j < 4; ++j)
          sacc[i][j] = mfma16(qf[i][kc], bfr[j], sacc[i][j]);
    }

    // causal mask (only diagonal-crossing key-tiles)
    if (kt >= 2 * qt) {
#pragma unroll
      for (int i = 0; i < 2; ++i)
#pragma unroll
        for (int j = 0; j < 4; ++j) {
          int key = kt * 64 + j * 16 + c;
#pragma unroll
          for (int r = 0; r < 4; ++r) {
            int qrow = qt * 128 + wid * 32 + i * 16 + q * 4 + r;
            if (key > qrow) sacc[i][j][r] = -1e30f;
          }
        }
    }

    // max-free softmax: P = exp(S); per-lane partial row-sums
#pragma unroll
    for (int i = 0; i < 2; ++i)
#pragma unroll
      for (int j = 0; j < 4; ++j)
#pragma unroll
        for (int r = 0; r < 4; ++r) {
          float p = __builtin_amdgcn_exp2f(sacc[i][j][r] * LOG2E);
          sacc[i][j][r] = p;
          lst[i][r] += p;
        }

    // P -> LDS (bf16), C-layout -> A-layout round trip (per-wave private slab)
#pragma unroll
    for (int i = 0; i < 2; ++i)
#pragma unroll
      for (int j = 0; j < 4; ++j) {
        uint32_t p01 = pk2(sacc[i][j][0], sacc[i][j][1]);
        uint32_t p23 = pk2(sacc[i][j][2], sacc[i][j][3]);
        u16* pp = Ps + wid * 2304 + (i * 16 + q * 4) * 72 + j * 16 + c;
        pp[0]   = (u16)p01;
        pp[72]  = (u16)(p01 >> 16);
        pp[144] = (u16)p23;
        pp[216] = (u16)(p23 >> 16);
      }

    // O^T += V^T @ P^T  (operand-swapped: m = d, n = qrow)
#pragma unroll
    for (int kc = 0; kc < 2; ++kc) {
      bf16x8 af[2], bv[8];
#pragma unroll
      for (int i = 0; i < 2; ++i)
        af[i] = *(const bf16x8*)((const char*)Ps + wid * 4608 + (i * 16 + c) * 144 +
                                 kc * 64 + q * 16);
#pragma unroll
      for (int jo = 0; jo < 8; ++jo) {
        int row = jo * 16 + c;
        int ch = ((kc << 2) | q) ^ (row & 7);
        bv[jo] = *(const bf16x8*)((const char*)Vs + row * 128 + ch * 16);
      }
#pragma unroll
      for (int i = 0; i < 2; ++i)
#pragma unroll
        for (int jo = 0; jo < 8; ++jo)
          oacc[i][jo] = mfma16(bv[jo], af[i], oacc[i][jo]);
    }
  }

  // epilogue: reduce l over c-lanes and store; store RAW O packed (4 contig d / lane)
#pragma unroll
  for (int i = 0; i < 2; ++i)
#pragma unroll
    for (int r = 0; r < 4; ++r) {
      float l = lst[i][r];
      l += __shfl_xor(l, 1);
      l += __shfl_xor(l, 2);
      l += __shfl_xor(l, 4);
      l += __shfl_xor(l, 8);
      if (c == 0)
        lp[(size_t)h * 2048 + qt * 128 + wid * 32 + i * 16 + q * 4 + r] = l;
    }
#pragma unroll
  for (int i = 0; i < 2; ++i) {
    int s = qt * 128 + wid * 32 + i * 16 + c;
#pragma unroll
    for (int jo = 0; jo < 8; ++jo) {
      uint2 o;
      o.x = pk2(oacc[i][jo][0], oacc[i][jo][1]);
      o.y = pk2(oacc[i][jo][2], oacc[i][jo][3]);
      *(uint2*)(Op + ((size_t)h * 2048 + s) * 128 + jo * 16 + q * 4) = o;
    }
  }
}

// ---------------- combine: AO = (sum Op_i)/(sum l_i), bf16 out [s][h*128+d] ----------
__global__ void attn_combine(const u16* __restrict__ Opb, const float* __restrict__ lpb,
                             u16* __restrict__ AO) {
  int g = blockIdx.x * 256 + threadIdx.x;   // 524288 threads, 8 elems each
  int row = g >> 4;                          // h*2048 + s
  int dd = (g & 15) * 8;
  int h = row >> 11, s = row & 2047;
  float lsum = lpb[row] + lpb[row + 32768] + lpb[row + 65536] + lpb[row + 98304];
  float inv = 1.0f / lsum;
  float acc[8] = {};
#pragma unroll
  for (int sp = 0; sp < 4; ++sp) {
    uint4 a = *(const uint4*)(Opb + (size_t)sp * 4194304 + (size_t)row * 128 + dd);
    const u16* pa = (const u16*)&a;
#pragma unroll
    for (int t = 0; t < 8; ++t) acc[t] += bf2f(pa[t]);
  }
  uint4 res;
  uint32_t* pr = (uint32_t*)&res;
#pragma unroll
  for (int t = 0; t < 4; ++t)
    pr[t] = pk2(acc[2 * t] * inv, acc[2 * t + 1] * inv);
  *(uint4*)(AO + (size_t)s * 2048 + h * 128 + dd) = res;
}

extern "C" void kernel_launch(void* const* d_in, const int* in_sizes, int n_in,
                              void* d_out, int out_size, void* d_ws, size_t ws_size,
                              hipStream_t stream) {
  const float* x  = (const float*)d_in[0];
  const float* Wq = (const float*)d_in[1];
  const float* bq = (const float*)d_in[2];
  const float* Wk = (const float*)d_in[3];
  const float* bk = (const float*)d_in[4];
  const float* Wv = (const float*)d_in[5];
  const float* bv = (const float*)d_in[6];
  const float* Wo = (const float*)d_in[7];
  const float* bo = (const float*)d_in[8];

  char* ws = (char*)d_ws;
  u16* xb = (u16*)(ws);                          // x bf16            0- 8 MB
  u16* wt = (u16*)(ws + (size_t)8  * 1048576);   // Wq/k/v/o^T bf16   8-40 MB
  u16* Qb = (u16*)(ws + (size_t)40 * 1048576);   // Q [h][s][d]      40-48 MB
  u16* Kb = (u16*)(ws + (size_t)48 * 1048576);   // K [h][s][d]      48-56 MB
  u16* Vt = (u16*)(ws + (size_t)56 * 1048576);   // V^T [h][d][s]    56-64 MB
  u16* AO = (u16*)(ws + (size_t)64 * 1048576);   // attn out [s][D]  64-72 MB
  // partial O x4 over dead regions [0,32 MB) (xb, Wq^T, Wk^T, Wv^T after QKV gemm);
  // row-sums l x4 (512 KB) in d_out (fp32 scratch, overwritten by final O-proj)
  u16* Opb = (u16*)(ws);
  float* lpb = (float*)d_out;

  cvt_bf16<<<4096, 256, 0, stream>>>(x, xb);
  transpose_cvt<<<dim3(32, 32, 4), 256, 0, stream>>>(Wq, Wk, Wv, Wo, wt);
  gemm_bt<<<dim3(48, 16), 256, 34816, stream>>>(xb, wt, 1, bq, bk, bv,
                                                nullptr, Qb, Kb, Vt);
  attn_kernel<<<1024, 256, 51200, stream>>>(Qb, Kb, Vt, Opb, lpb);
  attn_combine<<<2048, 256, 0, stream>>>(Opb, lpb, AO);
  gemm_bt<<<dim3(16, 16), 256, 34816, stream>>>(AO, wt + (size_t)3 * 2048 * 2048, 0,
                                                bo, nullptr, nullptr,
                                                (float*)d_out, nullptr, nullptr, nullptr);
}

// Round 6
// 247.376 us; speedup vs baseline: 1.3360x; 1.0595x over previous
//
#include <hip/hip_runtime.h>
#include <hip/hip_bf16.h>
#include <stdint.h>

typedef unsigned short u16;
typedef __attribute__((ext_vector_type(8))) __bf16 bf16x8;
typedef __attribute__((ext_vector_type(4))) float f32x4;

#define LOG2E 1.4426950408889634f

__device__ __forceinline__ float bf2f(u16 u) {
  union { uint32_t u; float f; } v; v.u = ((uint32_t)u) << 16;
  return v.f;
}

// packed cvt: two fp32 -> one u32 holding (lo=a, hi=b) bf16
__device__ __forceinline__ uint32_t pk2(float a, float b) {
  union { __hip_bfloat162 h; uint32_t u; } x;
  x.h = __float22bfloat162_rn(make_float2(a, b));
  return x.u;
}

__device__ __forceinline__ void gl_lds16(const void* g, void* l) {
  __builtin_amdgcn_global_load_lds((const __attribute__((address_space(1))) void*)g,
                                   (__attribute__((address_space(3))) void*)l,
                                   16, 0, 0);
}

__device__ __forceinline__ f32x4 mfma16(bf16x8 a, bf16x8 b, f32x4 c) {
  return __builtin_amdgcn_mfma_f32_16x16x32_bf16(a, b, c, 0, 0, 0);
}

// ---------------- fp32 -> bf16 elementwise (x) ----------------
__global__ void cvt_bf16(const float* __restrict__ src, u16* __restrict__ dst) {
  int i = (blockIdx.x * 256 + threadIdx.x) * 4;
  float4 f = *(const float4*)(src + i);
  uint2 o;
  o.x = pk2(f.x, f.y);
  o.y = pk2(f.z, f.w);
  *(uint2*)(dst + i) = o;
}

// ---------------- transpose + convert: W[k][n] fp32 -> Wt[n][k] bf16 ----------------
__global__ void transpose_cvt(const float* __restrict__ W0, const float* __restrict__ W1,
                              const float* __restrict__ W2, const float* __restrict__ W3,
                              u16* __restrict__ out) {
  __shared__ float tile[64][65];
  int z = blockIdx.z;
  const float* W = (z == 0) ? W0 : (z == 1) ? W1 : (z == 2) ? W2 : W3;
  u16* dst = out + (size_t)z * 2048 * 2048;
  int k0 = blockIdx.y * 64, n0 = blockIdx.x * 64;
  int lx = threadIdx.x & 63, ly = threadIdx.x >> 6;
#pragma unroll
  for (int p = 0; p < 16; ++p) {
    int row = p * 4 + ly;
    tile[row][lx] = W[(size_t)(k0 + row) * 2048 + n0 + lx];
  }
  __syncthreads();
  int kc = threadIdx.x & 7;        // 8-wide k chunk
  int rbase = threadIdx.x >> 3;    // 0..31
#pragma unroll
  for (int p = 0; p < 2; ++p) {
    int n = rbase + p * 32;        // n-local row
    uint4 o;
    o.x = pk2(tile[kc * 8 + 0][n], tile[kc * 8 + 1][n]);
    o.y = pk2(tile[kc * 8 + 2][n], tile[kc * 8 + 3][n]);
    o.z = pk2(tile[kc * 8 + 4][n], tile[kc * 8 + 5][n]);
    o.w = pk2(tile[kc * 8 + 6][n], tile[kc * 8 + 7][n]);
    *(uint4*)(dst + (size_t)(n0 + n) * 2048 + k0 + kc * 8) = o;
  }
}

// ---------------- bf16 GEMM, m97-style: QKV projections only ----------------
// tn in [0,48): proj=tn>>4, h=tn&15
//   proj 0: Q[h][s][d] = (acc+bq)/sqrt(128); proj 1: K[h][s][d]; proj 2: Vt[h][d][s]
__launch_bounds__(256, 2)
__global__ void gemm_bt(const u16* __restrict__ A, const u16* __restrict__ Bt,
                        const float* __restrict__ b0, const float* __restrict__ b1,
                        const float* __restrict__ b2,
                        u16* __restrict__ outQ, u16* __restrict__ outK,
                        u16* __restrict__ outVT) {
  extern __shared__ char smem[];
  u16* As = (u16*)smem;              // [128][64] bf16, 16B-chunk XOR swizzled
  u16* Bs = (u16*)(smem + 16384);
  const int K = 2048;
  const int tid = threadIdx.x;
  const int lane = tid & 63, wid = tid >> 6;
  const int c = lane & 15, q = lane >> 4;
  const int wm = wid >> 1, wn = wid & 1;
  const int tm = blockIdx.y, tn = blockIdx.x;
  const size_t Abase = (size_t)tm * 128 * K;
  const size_t Bbase = (size_t)tn * 128 * K;

  f32x4 acc[4][4] = {};

  for (int kt = 0; kt < K / 64; ++kt) {
#pragma unroll
    for (int t = 0; t < 4; ++t) {
      int slot = wid * 256 + t * 64 + lane;
      int row = slot >> 3, cs = slot & 7;
      int cc = cs ^ (row & 7);
      const u16* ga = A + Abase + (size_t)row * K + kt * 64 + cc * 8;
      gl_lds16(ga, (char*)As + (size_t)(wid * 256 + t * 64) * 16);
      const u16* gb = Bt + Bbase + (size_t)row * K + kt * 64 + cc * 8;
      gl_lds16(gb, (char*)Bs + (size_t)(wid * 256 + t * 64) * 16);
    }
    __syncthreads();
#pragma unroll
    for (int kc = 0; kc < 2; ++kc) {
      bf16x8 af[4], bfr[4];
#pragma unroll
      for (int i = 0; i < 4; ++i) {
        int rowa = wm * 64 + i * 16 + c;
        int cha = ((kc << 2) | q) ^ (rowa & 7);
        af[i] = *(const bf16x8*)((const char*)As + rowa * 128 + cha * 16);
        int rowb = wn * 64 + i * 16 + c;
        int chb = ((kc << 2) | q) ^ (rowb & 7);
        bfr[i] = *(const bf16x8*)((const char*)Bs + rowb * 128 + chb * 16);
      }
#pragma unroll
      for (int i = 0; i < 4; ++i)
#pragma unroll
        for (int j = 0; j < 4; ++j)
          acc[i][j] = mfma16(af[i], bfr[j], acc[i][j]);
    }
    __syncthreads();
  }

  int proj = tn >> 4;
  int h = tn & 15;
  const float* bias = (proj == 0) ? b0 : (proj == 1) ? b1 : b2;
  if (proj < 2) {
    u16* out = (proj == 0) ? outQ : outK;
    float scale = (proj == 0) ? 0.08838834764831845f : 1.0f;
#pragma unroll
    for (int i = 0; i < 4; ++i) {
      int s0 = tm * 128 + wm * 64 + i * 16 + q * 4;
#pragma unroll
      for (int j = 0; j < 4; ++j) {
        int d = wn * 64 + j * 16 + c;
        float bv = bias[h * 128 + d];
        uint32_t p01 = pk2((acc[i][j][0] + bv) * scale, (acc[i][j][1] + bv) * scale);
        uint32_t p23 = pk2((acc[i][j][2] + bv) * scale, (acc[i][j][3] + bv) * scale);
        u16* o = out + ((size_t)h * 2048 + s0) * 128 + d;
        o[0]   = (u16)p01;
        o[128] = (u16)(p01 >> 16);
        o[256] = (u16)p23;
        o[384] = (u16)(p23 >> 16);
      }
    }
  } else {
    // V: transpose via LDS -> Vt[h][d][s]
    u16* Cs = (u16*)smem;  // [128][136]
#pragma unroll
    for (int i = 0; i < 4; ++i) {
      int sl = wm * 64 + i * 16 + q * 4;
#pragma unroll
      for (int j = 0; j < 4; ++j) {
        int dl = wn * 64 + j * 16 + c;
        float bv = bias[h * 128 + dl];
        uint2 pk;
        pk.x = pk2(acc[i][j][0] + bv, acc[i][j][1] + bv);
        pk.y = pk2(acc[i][j][2] + bv, acc[i][j][3] + bv);
        *(uint2*)(Cs + dl * 136 + sl) = pk;
      }
    }
    __syncthreads();
#pragma unroll
    for (int rr = 0; rr < 8; ++rr) {
      int d = rr * 16 + (tid >> 4);
      int sc = (tid & 15) * 8;
      uint4 vv = *(const uint4*)(Cs + d * 136 + sc);
      *(uint4*)(outVT + ((size_t)(h * 128 + d)) * 2048 + tm * 128 + sc) = vv;
    }
  }
}

// ---------------- O-projection GEMM: 128x64 tiles for co-residency ----------------
// grid (32,16) = 512 blocks. Round-5 evidence: the old (16,16)=256-block version
// ran 1 block/CU (zero co-residency) -> latency-bound ~2x slower than QKV rate.
// 24 KB LDS + ~100 regs -> 4+ blocks/CU, latency hidden.
__launch_bounds__(256, 2)
__global__ void gemm_op(const u16* __restrict__ A, const u16* __restrict__ Bt,
                        const float* __restrict__ bias, float* __restrict__ out) {
  extern __shared__ char smem[];
  u16* As = (u16*)smem;              // [128][64]  16 KB
  u16* Bs = (u16*)(smem + 16384);    // [64][64]    8 KB
  const int K = 2048;
  const int tid = threadIdx.x;
  const int lane = tid & 63, wid = tid >> 6;
  const int c = lane & 15, q = lane >> 4;
  const int wm = wid >> 1, wn = wid & 1;
  const int tm = blockIdx.y, tn = blockIdx.x;
  const size_t Abase = (size_t)tm * 128 * K;
  const size_t Bbase = (size_t)tn * 64 * K;

  f32x4 acc[4][2] = {};

  for (int kt = 0; kt < K / 64; ++kt) {
#pragma unroll
    for (int t = 0; t < 4; ++t) {
      int slot = wid * 256 + t * 64 + lane;
      int row = slot >> 3, cs = slot & 7;
      int cc = cs ^ (row & 7);
      gl_lds16(A + Abase + (size_t)row * K + kt * 64 + cc * 8,
               (char*)As + (size_t)(wid * 256 + t * 64) * 16);
    }
#pragma unroll
    for (int t = 0; t < 2; ++t) {
      int slot = wid * 128 + t * 64 + lane;
      int row = slot >> 3, cs = slot & 7;
      int cc = cs ^ (row & 7);
      gl_lds16(Bt + Bbase + (size_t)row * K + kt * 64 + cc * 8,
               (char*)Bs + (size_t)(wid * 128 + t * 64) * 16);
    }
    __syncthreads();
#pragma unroll
    for (int kc = 0; kc < 2; ++kc) {
      bf16x8 af[4], bfr[2];
#pragma unroll
      for (int i = 0; i < 4; ++i) {
        int rowa = wm * 64 + i * 16 + c;
        int cha = ((kc << 2) | q) ^ (rowa & 7);
        af[i] = *(const bf16x8*)((const char*)As + rowa * 128 + cha * 16);
      }
#pragma unroll
      for (int j = 0; j < 2; ++j) {
        int rowb = wn * 32 + j * 16 + c;
        int chb = ((kc << 2) | q) ^ (rowb & 7);
        bfr[j] = *(const bf16x8*)((const char*)Bs + rowb * 128 + chb * 16);
      }
#pragma unroll
      for (int i = 0; i < 4; ++i)
#pragma unroll
        for (int j = 0; j < 2; ++j)
          acc[i][j] = mfma16(af[i], bfr[j], acc[i][j]);
    }
    __syncthreads();
  }

#pragma unroll
  for (int i = 0; i < 4; ++i) {
    int rowg = tm * 128 + wm * 64 + i * 16 + q * 4;
#pragma unroll
    for (int j = 0; j < 2; ++j) {
      int colg = tn * 64 + wn * 32 + j * 16 + c;
      float bv = bias[colg];
#pragma unroll
      for (int r = 0; r < 4; ++r)
        out[(size_t)(rowg + r) * 2048 + colg] = acc[i][j][r] + bv;
    }
  }
}

// ---------------- flash attention, causal, split-K(2), max-free softmax ----------------
// grid 512 (one fully co-resident round; split-4's 1024 blocks ran 2 sequential
// rounds of 8-tile paths = same 16-step critical path, 2x the partial traffic).
// Stores RAW partial O (bf16) + row-sum l (fp32 in d_out scratch); combine divides
// by (l0+l1). qt=0/split1 has l=0,O=0 rows — benign raw; NEVER normalize per-split.
// __launch_bounds__(256,2): (256,3) made the allocator spill ~50 regs (round 4:
// VGPR 84, WRITE_SIZE 94 MB, 2x slower). At 152 regs HW fits 3 blocks/CU anyway.
__launch_bounds__(256, 2)
__global__ void attn_kernel(const u16* __restrict__ Qb, const u16* __restrict__ Kb,
                            const u16* __restrict__ Vt,
                            u16* __restrict__ Opb, float* __restrict__ lpb) {
  extern __shared__ char smem[];
  u16* Ks = (u16*)smem;              // [64 keys][128 dk]  16 KB, swizzled
  u16* Vs = (u16*)(smem + 16384);    // [128 dk][64 keys]  16 KB, swizzled
  u16* Ps = (u16*)(smem + 32768);    // [4 waves][32][72]  18432 B
  int b = blockIdx.x;
  int split, qt, h;
  if (b < 256) { split = 0; qt = b >> 4; h = b & 15; }
  else { split = 1; int idx = b - 256; qt = 15 - (idx >> 4); h = idx & 15; }
  u16* Op = Opb + (size_t)split * 4194304;
  float* lp = lpb + (size_t)split * 32768;
  const int ktBase = split ? (qt + 1) : 0;
  const int ntiles = qt + 1;

  const int tid = threadIdx.x, lane = tid & 63, wid = tid >> 6;
  const int c = lane & 15, q = lane >> 4;

  // Q fragments in registers: wave owns rows [qt*128 + wid*32, +32)
  bf16x8 qf[2][4];
#pragma unroll
  for (int i = 0; i < 2; ++i) {
    int s = qt * 128 + wid * 32 + i * 16 + c;
    const u16* qrow = Qb + ((size_t)h * 2048 + s) * 128;
#pragma unroll
    for (int kc = 0; kc < 4; ++kc)
      qf[i][kc] = *(const bf16x8*)(qrow + kc * 32 + q * 8);
  }

  f32x4 oacc[2][8] = {};   // O^T: oacc[i][jo][r] = O[qrow=i*16+c][d=jo*16+q*4+r]
  float lst[2][4] = {};

  for (int tt = 0; tt < ntiles; ++tt) {
    const int kt = ktBase + tt;
    if (tt) __syncthreads();
#pragma unroll
    for (int t = 0; t < 4; ++t) {
      int slot = (wid * 4 + t) * 64 + lane;
      int rowk = slot >> 4, csk = slot & 15;
      int cck = csk ^ (rowk & 7);
      const u16* gk = Kb + ((size_t)h * 2048 + kt * 64 + rowk) * 128 + cck * 8;
      gl_lds16(gk, (char*)Ks + (size_t)((wid * 4 + t) * 64) * 16);
      int rowv = slot >> 3, csv = slot & 7;
      int ccv = csv ^ (rowv & 7);
      const u16* gv = Vt + ((size_t)(h * 128 + rowv)) * 2048 + kt * 64 + ccv * 8;
      gl_lds16(gv, (char*)Vs + (size_t)((wid * 4 + t) * 64) * 16);
    }
    __syncthreads();

    // S = Q K^T   (1/sqrt(dk) folded into Q)
    f32x4 sacc[2][4] = {};
#pragma unroll
    for (int kc = 0; kc < 4; ++kc) {
      bf16x8 bfr[4];
#pragma unroll
      for (int j = 0; j < 4; ++j) {
        int row = j * 16 + c;
        int ch = ((kc << 2) | q) ^ (row & 7);
        bfr[j] = *(const bf16x8*)((const char*)Ks + row * 256 + ch * 16);
      }
#pragma unroll
      for (int i = 0; i < 2; ++i)
#pragma unroll
        for (int j = 0; j < 4; ++j)
          sacc[i][j] = mfma16(qf[i][kc], bfr[j], sacc[i][j]);
    }

    // causal mask (only diagonal-crossing key-tiles)
    if (kt >= 2 * qt) {
#pragma unroll
      for (int i = 0; i < 2; ++i)
#pragma unroll
        for (int j = 0; j < 4; ++j) {
          int key = kt * 64 + j * 16 + c;
#pragma unroll
          for (int r = 0; r < 4; ++r) {
            int qrow = qt * 128 + wid * 32 + i * 16 + q * 4 + r;
            if (key > qrow) sacc[i][j][r] = -1e30f;
          }
        }
    }

    // max-free softmax: P = exp(S); per-lane partial row-sums
#pragma unroll
    for (int i = 0; i < 2; ++i)
#pragma unroll
      for (int j = 0; j < 4; ++j)
#pragma unroll
        for (int r = 0; r < 4; ++r) {
          float p = __builtin_amdgcn_exp2f(sacc[i][j][r] * LOG2E);
          sacc[i][j][r] = p;
          lst[i][r] += p;
        }

    // P -> LDS (bf16), C-layout -> A-layout round trip (per-wave private slab)
#pragma unroll
    for (int i = 0; i < 2; ++i)
#pragma unroll
      for (int j = 0; j < 4; ++j) {
        uint32_t p01 = pk2(sacc[i][j][0], sacc[i][j][1]);
        uint32_t p23 = pk2(sacc[i][j][2], sacc[i][j][3]);
        u16* pp = Ps + wid * 2304 + (i * 16 + q * 4) * 72 + j * 16 + c;
        pp[0]   = (u16)p01;
        pp[72]  = (u16)(p01 >> 16);
        pp[144] = (u16)p23;
        pp[216] = (u16)(p23 >> 16);
      }

    // O^T += V^T @ P^T  (operand-swapped: m = d, n = qrow)
#pragma unroll
    for (int kc = 0; kc < 2; ++kc) {
      bf16x8 af[2], bv[8];
#pragma unroll
      for (int i = 0; i < 2; ++i)
        af[i] = *(const bf16x8*)((const char*)Ps + wid * 4608 + (i * 16 + c) * 144 +
                                 kc * 64 + q * 16);
#pragma unroll
      for (int jo = 0; jo < 8; ++jo) {
        int row = jo * 16 + c;
        int ch = ((kc << 2) | q) ^ (row & 7);
        bv[jo] = *(const bf16x8*)((const char*)Vs + row * 128 + ch * 16);
      }
#pragma unroll
      for (int i = 0; i < 2; ++i)
#pragma unroll
        for (int jo = 0; jo < 8; ++jo)
          oacc[i][jo] = mfma16(bv[jo], af[i], oacc[i][jo]);
    }
  }

  // epilogue: reduce l over c-lanes and store; store RAW O packed (4 contig d / lane)
#pragma unroll
  for (int i = 0; i < 2; ++i)
#pragma unroll
    for (int r = 0; r < 4; ++r) {
      float l = lst[i][r];
      l += __shfl_xor(l, 1);
      l += __shfl_xor(l, 2);
      l += __shfl_xor(l, 4);
      l += __shfl_xor(l, 8);
      if (c == 0)
        lp[(size_t)h * 2048 + qt * 128 + wid * 32 + i * 16 + q * 4 + r] = l;
    }
#pragma unroll
  for (int i = 0; i < 2; ++i) {
    int s = qt * 128 + wid * 32 + i * 16 + c;
#pragma unroll
    for (int jo = 0; jo < 8; ++jo) {
      uint2 o;
      o.x = pk2(oacc[i][jo][0], oacc[i][jo][1]);
      o.y = pk2(oacc[i][jo][2], oacc[i][jo][3]);
      *(uint2*)(Op + ((size_t)h * 2048 + s) * 128 + jo * 16 + q * 4) = o;
    }
  }
}

// ---------------- combine: AO = (O0+O1)/(l0+l1), bf16 out [s][h*128+d] ----------------
__global__ void attn_combine(const u16* __restrict__ Opb, const float* __restrict__ lpb,
                             u16* __restrict__ AO) {
  int g = blockIdx.x * 256 + threadIdx.x;   // 524288 threads, 8 elems each
  int row = g >> 4;                          // h*2048 + s
  int dd = (g & 15) * 8;
  int h = row >> 11, s = row & 2047;
  float inv = 1.0f / (lpb[row] + lpb[row + 32768]);
  uint4 a = *(const uint4*)(Opb + (size_t)row * 128 + dd);
  uint4 bb = *(const uint4*)(Opb + 4194304 + (size_t)row * 128 + dd);
  const u16* pa = (const u16*)&a;
  const u16* pb = (const u16*)&bb;
  uint4 res;
  uint32_t* pr = (uint32_t*)&res;
#pragma unroll
  for (int t = 0; t < 4; ++t)
    pr[t] = pk2((bf2f(pa[2 * t]) + bf2f(pb[2 * t])) * inv,
                (bf2f(pa[2 * t + 1]) + bf2f(pb[2 * t + 1])) * inv);
  *(uint4*)(AO + (size_t)s * 2048 + h * 128 + dd) = res;
}

extern "C" void kernel_launch(void* const* d_in, const int* in_sizes, int n_in,
                              void* d_out, int out_size, void* d_ws, size_t ws_size,
                              hipStream_t stream) {
  const float* x  = (const float*)d_in[0];
  const float* Wq = (const float*)d_in[1];
  const float* bq = (const float*)d_in[2];
  const float* Wk = (const float*)d_in[3];
  const float* bk = (const float*)d_in[4];
  const float* Wv = (const float*)d_in[5];
  const float* bv = (const float*)d_in[6];
  const float* Wo = (const float*)d_in[7];
  const float* bo = (const float*)d_in[8];

  char* ws = (char*)d_ws;
  u16* xb = (u16*)(ws);                          // x bf16            0- 8 MB
  u16* wt = (u16*)(ws + (size_t)8  * 1048576);   // Wq/k/v/o^T bf16   8-40 MB
  u16* Qb = (u16*)(ws + (size_t)40 * 1048576);   // Q [h][s][d]      40-48 MB
  u16* Kb = (u16*)(ws + (size_t)48 * 1048576);   // K [h][s][d]      48-56 MB
  u16* Vt = (u16*)(ws + (size_t)56 * 1048576);   // V^T [h][d][s]    56-64 MB
  u16* AO = (u16*)(ws + (size_t)64 * 1048576);   // attn out [s][D]  64-72 MB
  // partial O x2 over dead regions [0,16 MB) (xb, Wq^T after QKV gemm);
  // row-sums l x2 (256 KB) in d_out (fp32 scratch, overwritten by final O-proj)
  u16* Opb = (u16*)(ws);
  float* lpb = (float*)d_out;

  cvt_bf16<<<4096, 256, 0, stream>>>(x, xb);
  transpose_cvt<<<dim3(32, 32, 4), 256, 0, stream>>>(Wq, Wk, Wv, Wo, wt);
  gemm_bt<<<dim3(48, 16), 256, 34816, stream>>>(xb, wt, bq, bk, bv, Qb, Kb, Vt);
  attn_kernel<<<512, 256, 51200, stream>>>(Qb, Kb, Vt, Opb, lpb);
  attn_combine<<<2048, 256, 0, stream>>>(Opb, lpb, AO);
  gemm_op<<<dim3(32, 16), 256, 24576, stream>>>(AO, wt + (size_t)3 * 2048 * 2048,
                                                bo, (float*)d_out);
}